// Round 4
// baseline (25.683 us; speedup 1.0000x reference)
//
#include <hip/hip_runtime.h>

#define SEQ 4096
#define DIM 1024

typedef __attribute__((ext_vector_type(8))) short short8;
typedef __attribute__((ext_vector_type(4))) float f32x4;

// f32 -> bf16 with round-to-nearest-even
__device__ __forceinline__ unsigned short f2bf(float f) {
    unsigned int u = __float_as_uint(f);
    u += 0x7FFF + ((u >> 16) & 1);
    return (unsigned short)(u >> 16);
}

__device__ __forceinline__ short8 cvt8(float4 a, float4 b) {
    short8 r;
    r[0] = (short)f2bf(a.x); r[1] = (short)f2bf(a.y);
    r[2] = (short)f2bf(a.z); r[3] = (short)f2bf(a.w);
    r[4] = (short)f2bf(b.x); r[5] = (short)f2bf(b.y);
    r[6] = (short)f2bf(b.z); r[7] = (short)f2bf(b.w);
    return r;
}

// One fused kernel. Grid (8 col-tiles, 4 row-quads) x 512 thr.
// Block (ct,rq): out rows rq*16..+15 (= batches rq*2,rq*2+1 x 8 buckets),
// cols ct*128..+127. Fully self-sufficient: no cross-block traffic.
__global__ __launch_bounds__(512) void k_fused(
    const float* __restrict__ latent,   // [8][SEQ][DIM]
    const int*   __restrict__ mask,     // [8][SEQ]
    const float* __restrict__ Wm,       // [DIM][DIM] row-major
    const float* __restrict__ bias,     // [DIM]
    float*       __restrict__ out)      // [64][DIM]
{
    __shared__ unsigned short sA[16 * 1024];  // bf16 mean rows, swizzled 16B units
    __shared__ int s_pos[2][8];

    const int ct   = blockIdx.x;      // 0..7
    const int rq   = blockIdx.y;      // 0..3
    const int b0   = rq * 2;
    const int tid  = threadIdx.x;
    const int lane = tid & 63;
    const int wid  = tid >> 6;        // 0..7

    // ---- Phase A: waves 0,1 scan batches b0,b0+1 for first-8 one-positions ----
    if (wid < 2) {
        const int b = b0 + wid;
        if (lane < 8) s_pos[wid][lane] = SEQ;   // wave-local init, own wave writes after
        int carry = 0;
        for (int ch = 0; ch < SEQ / 256 && carry < 8; ++ch) {
            const int4 m = *(const int4*)(mask + (size_t)b * SEQ + ch * 256 + lane * 4);
            const int cnt = m.x + m.y + m.z + m.w;
            int v = cnt;
            #pragma unroll
            for (int off = 1; off < 64; off <<= 1) {
                int o = __shfl_up(v, off, 64);
                if (lane >= off) v += o;
            }
            const int excl = carry + v - cnt;   // ones strictly before my 4 ints
            if (excl < 8 && cnt > 0) {
                int vals[4] = {m.x, m.y, m.z, m.w};
                int rank = excl;
                #pragma unroll
                for (int i = 0; i < 4; ++i) {
                    if (vals[i]) {
                        if (rank < 8) s_pos[wid][rank] = ch * 256 + lane * 4 + i;
                        ++rank;
                    }
                }
            }
            carry += __shfl(v, 63, 64);
        }
    }
    __syncthreads();

    // ---- Phase B: 16 bucket means -> bf16 LDS (swizzled) ----
    {
        const int rg  = tid >> 5;     // local row 0..15
        const int l32 = tid & 31;     // 32 f32 of the row per lane
        const int bb  = rg >> 3;      // 0/1
        const int p   = rg & 7;
        const int start = (p == 0) ? 0 : s_pos[bb][p - 1] + 1;
        const int endi  = min(s_pos[bb][p], SEQ - 1);
        const float inv = (endi >= start) ? 1.0f / (float)(endi - start + 1) : 0.0f;

        float a[32];
        #pragma unroll
        for (int j = 0; j < 32; ++j) a[j] = 0.f;
        const float* base = latent + (size_t)(b0 + bb) * SEQ * DIM + l32 * 32;
        for (int s = start; s <= endi; ++s) {
            const float4* rp = (const float4*)(base + (size_t)s * DIM);
            #pragma unroll
            for (int f = 0; f < 8; ++f) {
                float4 v = rp[f];
                a[f*4+0] += v.x; a[f*4+1] += v.y; a[f*4+2] += v.z; a[f*4+3] += v.w;
            }
        }
        #pragma unroll
        for (int t = 0; t < 4; ++t) {
            short8 pk;
            #pragma unroll
            for (int j = 0; j < 8; ++j) pk[j] = (short)f2bf(a[t*8+j] * inv);
            const int u  = l32 * 4 + t;          // 16B unit index 0..127
            const int su = u ^ (rg & 7);         // bank-spread swizzle
            *(short8*)&sA[rg * 1024 + su * 8] = pk;
        }
    }
    __syncthreads();

    // ---- Phase C: MFMA GEMM, one 16x16 subtile per wave ----
    const int l15 = lane & 15;
    const int lk  = lane >> 4;                   // 0..3 k-group
    const int col = ct * 128 + wid * 16 + l15;
    const float* wrow = Wm + (size_t)col * DIM;

    f32x4 acc = {0.f, 0.f, 0.f, 0.f};
    #pragma unroll 8
    for (int ks = 0; ks < 32; ++ks) {
        // A-frag: lane holds mean[row=l15][k = ks*32 + lk*8 .. +8]
        const int u  = ks * 4 + lk;
        const int su = u ^ (l15 & 7);
        short8 afrag = *(const short8*)&sA[l15 * 1024 + su * 8];
        // B-frag: lane holds W[col][same 8 k] (contiguous global read)
        const float4 w0 = *(const float4*)(wrow + ks * 32 + lk * 8);
        const float4 w1 = *(const float4*)(wrow + ks * 32 + lk * 8 + 4);
        short8 bfrag = cvt8(w0, w1);
        acc = __builtin_amdgcn_mfma_f32_16x16x32_bf16(afrag, bfrag, acc, 0, 0, 0);
    }

    // D layout: col = lane&15, row = (lane>>4)*4 + j
    const float bv = bias[col];
    const int rbase = rq * 16 + lk * 4;
    #pragma unroll
    for (int j = 0; j < 4; ++j)
        out[(size_t)(rbase + j) * DIM + col] = acc[j] + bv;
}

extern "C" void kernel_launch(void* const* d_in, const int* in_sizes, int n_in,
                              void* d_out, int out_size, void* d_ws, size_t ws_size,
                              hipStream_t stream) {
    const float* latent = (const float*)d_in[0];   // (8,4096,1024) f32
    const int*   mask   = (const int*)d_in[1];     // (8,4096,1) int32
    const float* Wm     = (const float*)d_in[2];   // (1024,1024) f32
    const float* bias   = (const float*)d_in[3];   // (1024,) f32
    float* out = (float*)d_out;                    // (8,8,1024) f32

    k_fused<<<dim3(8, 4), 512, 0, stream>>>(latent, mask, Wm, bias, out);
}

// Round 5
// 14.141 us; speedup vs baseline: 1.8162x; 1.8162x over previous
//
#include <hip/hip_runtime.h>

#define SEQ 4096
#define DIM 1024
#define NBAT 8
#define NP  8
#define M   64

typedef __attribute__((ext_vector_type(8))) short short8;
typedef __attribute__((ext_vector_type(4))) float f32x4;
typedef __attribute__((ext_vector_type(4))) unsigned short us4;

// f32 -> bf16 round-to-nearest-even
__device__ __forceinline__ unsigned short f2bf(float f) {
    unsigned int u = __float_as_uint(f);
    u += 0x7FFF + ((u >> 16) & 1);
    return (unsigned short)(u >> 16);
}

// ---------------------------------------------------------------------------
// k_prep: grid 320 x 256.
//  blocks 0..63   : bucket mean for (b = blk>>3, p = blk&7) -> wsA in MFMA
//                   A-fragment-linear layout: elem(rt,ks,lane,j) at
//                   (rt*32+ks)*512 + lane*8 + j, where row=rt*16+(lane&15),
//                   k = ks*32 + (lane>>4)*8 + j.   (64x1024 bf16 = 128 KB)
//  blocks 64..319 : W f32->bf16 into wsB, B-fragment-linear layout:
//                   (ct*32+ks)*512 + lane*8 + j, col=ct*16+(lane&15),
//                   k = ks*32 + (lane>>4)*8 + j.   (1024x1024 bf16 = 2 MB)
// ---------------------------------------------------------------------------
__global__ __launch_bounds__(256) void k_prep(
    const float* __restrict__ latent,   // [8][SEQ][DIM]
    const int*   __restrict__ mask,     // [8][SEQ]
    const float* __restrict__ Wm,       // [DIM][DIM]
    unsigned short* __restrict__ wsA,
    unsigned short* __restrict__ wsB)
{
    const int blk  = blockIdx.x;
    const int tid  = threadIdx.x;
    const int lane = tid & 63;
    const int wid  = tid >> 6;

    if (blk < 64) {
        const int b = blk >> 3;
        const int p = blk & 7;
        __shared__ int s_pos[8];

        // wave 0: chunked early-exit scan for first-8 one positions
        if (wid == 0) {
            if (lane < 8) s_pos[lane] = SEQ;
            int carry = 0;
            for (int ch = 0; ch < SEQ / 256 && carry < 8; ++ch) {
                const int4 m = *(const int4*)(mask + (size_t)b * SEQ + ch * 256 + lane * 4);
                const int cnt = m.x + m.y + m.z + m.w;
                int v = cnt;
                #pragma unroll
                for (int off = 1; off < 64; off <<= 1) {
                    int o = __shfl_up(v, off, 64);
                    if (lane >= off) v += o;
                }
                const int excl = carry + v - cnt;
                if (excl < 8 && cnt > 0) {
                    int vals[4] = {m.x, m.y, m.z, m.w};
                    int rank = excl;
                    #pragma unroll
                    for (int i = 0; i < 4; ++i) {
                        if (vals[i]) {
                            if (rank < 8) s_pos[rank] = ch * 256 + lane * 4 + i;
                            ++rank;
                        }
                    }
                }
                carry += __shfl(v, 63, 64);
            }
        }
        __syncthreads();

        const int start = (p == 0) ? 0 : s_pos[p - 1] + 1;
        const int endi  = min(s_pos[p], SEQ - 1);
        const float4* lb = (const float4*)(latent + (size_t)b * SEQ * DIM);
        float4 acc = make_float4(0.f, 0.f, 0.f, 0.f);
        for (int s = start; s <= endi; ++s) {        // coalesced: tid = f4 col
            float4 v = lb[(size_t)s * (DIM / 4) + tid];
            acc.x += v.x; acc.y += v.y; acc.z += v.z; acc.w += v.w;
        }
        const float inv = (endi >= start) ? 1.0f / (float)(endi - start + 1) : 0.0f;

        const int r   = blk;            // output row = b*8+p
        const int rt  = r >> 4, l15 = r & 15;
        const int k0  = tid * 4;
        const int ks  = k0 >> 5;
        const int lk  = (k0 >> 3) & 3;
        const int j   = k0 & 7;         // 0 or 4
        us4 o = { f2bf(acc.x * inv), f2bf(acc.y * inv),
                  f2bf(acc.z * inv), f2bf(acc.w * inv) };
        *(us4*)&wsA[(size_t)(rt * 32 + ks) * 512 + (lk * 16 + l15) * 8 + j] = o;
    } else {
        const int w   = blk - 64;       // 0..255 -> W rows (out cols) 4w..4w+3
        const int col = w * 4 + wid;    // wave wid owns one col
        const int ct  = col >> 4, l15 = col & 15;
        const float* wr = Wm + (size_t)col * DIM;
        #pragma unroll
        for (int q = 0; q < 4; ++q) {
            const int k = q * 256 + lane * 4;       // coalesced 1KB per instr
            float4 v = *(const float4*)(wr + k);
            const int ks = k >> 5;
            const int lk = (k >> 3) & 3;
            const int j  = k & 7;
            us4 o = { f2bf(v.x), f2bf(v.y), f2bf(v.z), f2bf(v.w) };
            *(us4*)&wsB[(size_t)(ct * 32 + ks) * 512 + (lk * 16 + l15) * 8 + j] = o;
        }
    }
}

// ---------------------------------------------------------------------------
// k_gemm: grid 64 x 512. Block ct: out cols ct*16..+15, all 64 rows.
// 8 waves: (rt = wid&3, kh = wid>>2); wave does K-half kh for row-tile rt,
// 16 MFMAs, then deterministic in-block pair reduce + bias + store.
// ---------------------------------------------------------------------------
__global__ __launch_bounds__(512) void k_gemm(
    const unsigned short* __restrict__ wsA,
    const unsigned short* __restrict__ wsB,
    const float* __restrict__ bias,
    float* __restrict__ out)            // [64][DIM]
{
    __shared__ f32x4 sred[4][64];
    const int ct   = blockIdx.x;
    const int tid  = threadIdx.x;
    const int lane = tid & 63;
    const int wid  = tid >> 6;
    const int rt   = wid & 3;
    const int kh   = wid >> 2;

    const short8* A = (const short8*)wsA;   // idx = (rt*32+ks)*64 + lane
    const short8* B = (const short8*)wsB;   // idx = (ct*32+ks)*64 + lane

    f32x4 acc = {0.f, 0.f, 0.f, 0.f};
    #pragma unroll
    for (int s = 0; s < 16; ++s) {
        const int ks = kh * 16 + s;
        short8 a = A[(size_t)(rt * 32 + ks) * 64 + lane];
        short8 b = B[(size_t)(ct * 32 + ks) * 64 + lane];
        acc = __builtin_amdgcn_mfma_f32_16x16x32_bf16(a, b, acc, 0, 0, 0);
    }

    if (kh == 1) sred[rt][lane] = acc;
    __syncthreads();
    if (kh == 0) {
        f32x4 o = sred[rt][lane];
        acc = acc + o;                       // fixed order: deterministic
        const int l15 = lane & 15, lk = lane >> 4;
        const int col = ct * 16 + l15;
        const float bv = bias[col];
        #pragma unroll
        for (int j = 0; j < 4; ++j)          // D: row=(lane>>4)*4+j, col=lane&15
            out[(size_t)(rt * 16 + lk * 4 + j) * DIM + col] = acc[j] + bv;
    }
}

extern "C" void kernel_launch(void* const* d_in, const int* in_sizes, int n_in,
                              void* d_out, int out_size, void* d_ws, size_t ws_size,
                              hipStream_t stream) {
    const float* latent = (const float*)d_in[0];   // (8,4096,1024) f32
    const int*   mask   = (const int*)d_in[1];     // (8,4096,1) int32
    const float* Wm     = (const float*)d_in[2];   // (1024,1024) f32
    const float* bias   = (const float*)d_in[3];   // (1024,) f32
    float* out = (float*)d_out;                    // (8,8,1024) f32

    unsigned short* wsA = (unsigned short*)d_ws;   // 128 KB
    unsigned short* wsB = wsA + (size_t)M * DIM;   // 2 MB

    k_prep<<<320, 256, 0, stream>>>(latent, mask, Wm, wsA, wsB);
    k_gemm<<<64, 512, 0, stream>>>(wsA, wsB, bias, out);
}